// Round 5
// baseline (105.040 us; speedup 1.0000x reference)
//
#include <hip/hip_runtime.h>
#include <math.h>

// DetectionLayer: x(32,255,76,76) f32 -> out(32,17328,85) f32
// Block (256 thr) = (b, row i, anchor a, channel-half h).
//   h=0: channels [0,43)  (includes the 4 corner channels)
//   h=1: channels [43,85)
// LDS = 43 x 77 x 4B = 13.2KB -> 8 blocks/CU (wave-capped, 100% theoretical).
// Phase 1: SCALAR loads -> lane-stride-1 LDS writes (zero bank conflicts),
//          global reads coalesced along j (full 304B rows: fetch-efficient).
// Phase 2: raster over 76 rows x nattr attrs; LDS reads at lane-stride 77
//          (77%32=13, coprime -> conflict-free); stores wave-coalesced.
// XCD swizzle: logical order (b,a,i,h), h fastest; 14592%8==0 -> bijective.

#define NCH    255
#define NATTR  85
#define HW     5776
#define GW     76
#define NBATCH 32
#define PADJ   77
#define BLOCK  256
#define NWG    (NBATCH * 3 * GW * 2)   // 14592
#define CHUNK  (NWG / 8)               // 1824

__device__ __forceinline__ float sigm(float x) {
    return __builtin_amdgcn_rcpf(1.0f + __expf(-x));
}

__global__ __launch_bounds__(BLOCK) void det_kernel(const float* __restrict__ in,
                                                    float* __restrict__ out) {
    int hw = blockIdx.x;
    int L  = (hw & 7) * CHUNK + (hw >> 3);
    int h  = L & 1;
    int L2 = L >> 1;
    int i  = L2 % GW;
    int ba = L2 / GW;
    int a  = ba % 3;
    int b  = ba / 3;

    const int c0 = 43 * h;

    __shared__ float lds[43 * PADJ];

    const float* __restrict__ src =
        in + (size_t)(b * NCH + a * NATTR + c0) * HW + (size_t)i * GW;

    const float anc_w = ((a == 0) ? 10.f : (a == 1) ? 16.f : 33.f) * (0.5f / 608.f);
    const float anc_h = ((a == 0) ? 13.f : (a == 1) ? 30.f : 23.f) * (0.5f / 608.f);
    const float fi = (float)i;

    // output element: (b*17328 + i*228 + a)*85 + c0 + 255*r + t
    float* __restrict__ dst =
        out + ((size_t)b * 17328 + (size_t)i * 228 + a) * NATTR + c0;

    if (h == 0) {
        // ---- phase 1: 43 channels, scalar, lane-stride-1 LDS writes ----
        #pragma unroll 2
        for (int e = threadIdx.x; e < 43 * GW; e += BLOCK) {
            int c = e / GW;
            int j = e - c * GW;
            lds[c * PADJ + j] = src[(size_t)c * HW + j];
        }
        __syncthreads();

        // ---- phase 2: 76 rows x 43 attrs (corners inline, 4/43 lanes) ----
        #pragma unroll 2
        for (int e = threadIdx.x; e < 43 * GW; e += BLOCK) {
            int r = e / 43;
            int t = e - r * 43;
            float val;
            if (t >= 4) {
                val = sigm(lds[t * PADJ + r]);
            } else {
                float ixy, wh2;
                if (t & 1) {
                    ixy = (sigm(lds[1 * PADJ + r]) * 1.05f - 0.025f + fi) * (1.0f / 76.0f);
                    wh2 = __expf(lds[3 * PADJ + r]) * anc_h;
                } else {
                    ixy = (sigm(lds[0 * PADJ + r]) * 1.05f - 0.025f + (float)r) * (1.0f / 76.0f);
                    wh2 = __expf(lds[2 * PADJ + r]) * anc_w;
                }
                val = (t < 2) ? (ixy - wh2) : (ixy + wh2);
            }
            dst[(size_t)r * 255 + t] = val;
        }
    } else {
        // ---- phase 1: 42 channels ----
        #pragma unroll 2
        for (int e = threadIdx.x; e < 42 * GW; e += BLOCK) {
            int c = e / GW;
            int j = e - c * GW;
            lds[c * PADJ + j] = src[(size_t)c * HW + j];
        }
        __syncthreads();

        // ---- phase 2: 76 rows x 42 attrs, pure sigmoid ----
        #pragma unroll 2
        for (int e = threadIdx.x; e < 42 * GW; e += BLOCK) {
            int r = e / 42;
            int t = e - r * 42;
            dst[(size_t)r * 255 + t] = sigm(lds[t * PADJ + r]);
        }
    }
}

extern "C" void kernel_launch(void* const* d_in, const int* in_sizes, int n_in,
                              void* d_out, int out_size, void* d_ws, size_t ws_size,
                              hipStream_t stream) {
    const float* x = (const float*)d_in[0];
    float* out = (float*)d_out;
    det_kernel<<<NWG, BLOCK, 0, stream>>>(x, out);
}